// Round 3
// 461.459 us; speedup vs baseline: 1.0488x; 1.0488x over previous
//
#include <hip/hip_runtime.h>
#include <math.h>

#define IN_DIM  8192
#define OUT_DIM 8192
#define BATCH   8192
#define RPB     2      // batch rows per block
#define T       1024   // threads per block

typedef float f32x4 __attribute__((ext_vector_type(4)));  // for nontemporal store

// GATE_COEFFS columns (g0,g1,g2,g3) per row i
__device__ __constant__ float GC0[16] = {0,0,0,0, 0,0,0,0, 1,1,1,1, 1,1,1,1};
__device__ __constant__ float GC1[16] = {0,0,1,1, 0,0,1,1, -1,-1,0,0, -1,-1,0,0};
__device__ __constant__ float GC2[16] = {0,0,0,0, 1,1,1,1, -1,-1,-1,-1, 0,0,0,0};
__device__ __constant__ float GC3[16] = {0,1,-1,0, -1,0,-2,-1, 1,2,0,1, 0,1,-1,0};

// Kernel 1: c[j] = softmax(weight[j,:]) @ GATE_COEFFS  -> float4 per column
__global__ __launch_bounds__(256) void compute_c_kernel(
    const float* __restrict__ weight, float4* __restrict__ c)
{
    int row = blockIdx.x * 256 + threadIdx.x;
    if (row >= OUT_DIM) return;
    const float* wr = weight + (size_t)row * 16;
    float v[16];
    float m = -1e30f;
#pragma unroll
    for (int i = 0; i < 16; ++i) { v[i] = wr[i]; m = fmaxf(m, v[i]); }
    float s = 0.f;
#pragma unroll
    for (int i = 0; i < 16; ++i) { v[i] = __expf(v[i] - m); s += v[i]; }
    float inv = 1.0f / s;
    float c0 = 0.f, c1 = 0.f, c2 = 0.f, c3 = 0.f;
#pragma unroll
    for (int i = 0; i < 16; ++i) {
        c0 = fmaf(v[i], GC0[i], c0);
        c1 = fmaf(v[i], GC1[i], c1);
        c2 = fmaf(v[i], GC2[i], c2);
        c3 = fmaf(v[i], GC3[i], c3);
    }
    c[row] = make_float4(c0 * inv, c1 * inv, c2 * inv, c3 * inv);
}

// Kernel 2: 2 batch rows per block (64 KB LDS), 1024 threads.
// 2 blocks/CU (LDS- and thread-limited) -> 32 waves/CU = 100% occupancy.
// idx/c loads amortized over 2 rows; out stored non-temporally.
__global__ __launch_bounds__(T, 8) void gate_main_kernel(
    const float* __restrict__ x,
    const float4* __restrict__ c,
    const int4* __restrict__ ia4,
    const int4* __restrict__ ib4,
    float* __restrict__ out)
{
    __shared__ float4 xrow4[RPB * IN_DIM / 4];        // 64 KB
    float* xrow = (float*)xrow4;
    const size_t b0 = (size_t)blockIdx.x * RPB;

    // Fill: 2 adjacent x rows are contiguous in memory -> one coalesced sweep.
    const float4* xr4 = (const float4*)(x + b0 * IN_DIM);
#pragma unroll
    for (int i = 0; i < (RPB * IN_DIM / 4) / T; ++i)   // 4 iters
        xrow4[i * T + threadIdx.x] = xr4[i * T + threadIdx.x];
    __syncthreads();

    const float* x0 = xrow;
    const float* x1 = xrow + IN_DIM;
    f32x4* orow0 = (f32x4*)(out + b0 * OUT_DIM);
    f32x4* orow1 = orow0 + (OUT_DIM / 4);

#pragma unroll
    for (int it = 0; it < OUT_DIM / 4 / T; ++it) {     // 2 iters
        int j4 = it * T + threadIdx.x;
        int4 ia = ia4[j4];
        int4 ib = ib4[j4];
        float4 cA = c[4 * j4 + 0];
        float4 cB = c[4 * j4 + 1];
        float4 cC = c[4 * j4 + 2];
        float4 cD = c[4 * j4 + 3];

        // row 0
        {
            float a0 = x0[ia.x], v0 = x0[ib.x];
            float a1 = x0[ia.y], v1 = x0[ib.y];
            float a2 = x0[ia.z], v2 = x0[ib.z];
            float a3 = x0[ia.w], v3 = x0[ib.w];
            f32x4 o;
            o.x = fmaf(a0, fmaf(v0, cA.w, cA.y), fmaf(v0, cA.z, cA.x));
            o.y = fmaf(a1, fmaf(v1, cB.w, cB.y), fmaf(v1, cB.z, cB.x));
            o.z = fmaf(a2, fmaf(v2, cC.w, cC.y), fmaf(v2, cC.z, cC.x));
            o.w = fmaf(a3, fmaf(v3, cD.w, cD.y), fmaf(v3, cD.z, cD.x));
            __builtin_nontemporal_store(o, &orow0[j4]);
        }
        // row 1 (reuses ia/ib/c registers)
        {
            float a0 = x1[ia.x], v0 = x1[ib.x];
            float a1 = x1[ia.y], v1 = x1[ib.y];
            float a2 = x1[ia.z], v2 = x1[ib.z];
            float a3 = x1[ia.w], v3 = x1[ib.w];
            f32x4 o;
            o.x = fmaf(a0, fmaf(v0, cA.w, cA.y), fmaf(v0, cA.z, cA.x));
            o.y = fmaf(a1, fmaf(v1, cB.w, cB.y), fmaf(v1, cB.z, cB.x));
            o.z = fmaf(a2, fmaf(v2, cC.w, cC.y), fmaf(v2, cC.z, cC.x));
            o.w = fmaf(a3, fmaf(v3, cD.w, cD.y), fmaf(v3, cD.z, cD.x));
            __builtin_nontemporal_store(o, &orow1[j4]);
        }
    }
}

extern "C" void kernel_launch(void* const* d_in, const int* in_sizes, int n_in,
                              void* d_out, int out_size, void* d_ws, size_t ws_size,
                              hipStream_t stream) {
    const float* x      = (const float*)d_in[0];
    const float* weight = (const float*)d_in[1];
    const int*   idx_a  = (const int*)d_in[2];
    const int*   idx_b  = (const int*)d_in[3];
    float* out = (float*)d_out;

    float4* c = (float4*)d_ws;  // OUT_DIM float4 = 128 KB scratch

    compute_c_kernel<<<OUT_DIM / 256, 256, 0, stream>>>(weight, c);
    gate_main_kernel<<<BATCH / RPB, T, 0, stream>>>(
        x, c, (const int4*)idx_a, (const int4*)idx_b, out);
}

// Round 4
// 445.877 us; speedup vs baseline: 1.0854x; 1.0349x over previous
//
#include <hip/hip_runtime.h>
#include <math.h>

#define IN_DIM  8192
#define OUT_DIM 8192
#define BATCH   8192
#define ROWS    16     // batch rows per block (pipelined)
#define T       1024   // threads per block

// GATE_COEFFS columns (g0,g1,g2,g3) per row i
__device__ __constant__ float GC0[16] = {0,0,0,0, 0,0,0,0, 1,1,1,1, 1,1,1,1};
__device__ __constant__ float GC1[16] = {0,0,1,1, 0,0,1,1, -1,-1,0,0, -1,-1,0,0};
__device__ __constant__ float GC2[16] = {0,0,0,0, 1,1,1,1, -1,-1,-1,-1, 0,0,0,0};
__device__ __constant__ float GC3[16] = {0,1,-1,0, -1,0,-2,-1, 1,2,0,1, 0,1,-1,0};

// Kernel 1: c[j] = softmax(weight[j,:]) @ GATE_COEFFS  -> float4 per column
__global__ __launch_bounds__(256) void compute_c_kernel(
    const float* __restrict__ weight, float4* __restrict__ c)
{
    int row = blockIdx.x * 256 + threadIdx.x;
    if (row >= OUT_DIM) return;
    const float* wr = weight + (size_t)row * 16;
    float v[16];
    float m = -1e30f;
#pragma unroll
    for (int i = 0; i < 16; ++i) { v[i] = wr[i]; m = fmaxf(m, v[i]); }
    float s = 0.f;
#pragma unroll
    for (int i = 0; i < 16; ++i) { v[i] = __expf(v[i] - m); s += v[i]; }
    float inv = 1.0f / s;
    float c0 = 0.f, c1 = 0.f, c2 = 0.f, c3 = 0.f;
#pragma unroll
    for (int i = 0; i < 16; ++i) {
        c0 = fmaf(v[i], GC0[i], c0);
        c1 = fmaf(v[i], GC1[i], c1);
        c2 = fmaf(v[i], GC2[i], c2);
        c3 = fmaf(v[i], GC3[i], c3);
    }
    c[row] = make_float4(c0 * inv, c1 * inv, c2 * inv, c3 * inv);
}

// Kernel 2: persistent block over 16 batch rows.
// - idx/c register-resident for the block's lifetime (loaded once, 48 VGPR)
// - double-buffered x row in LDS (2 x 32 KB), T14 async-stage split:
//   issue next-row loads -> gather/compute current row -> ds_write -> barrier
// - one __syncthreads per row
__global__ __launch_bounds__(T, 4) void gate_main_kernel(
    const float* __restrict__ x,
    const float4* __restrict__ c,
    const int4* __restrict__ ia4,
    const int4* __restrict__ ib4,
    float4* __restrict__ out)
{
    __shared__ float buf[2][IN_DIM];          // 64 KB
    const int tid = threadIdx.x;
    const size_t r0 = (size_t)blockIdx.x * ROWS;

    // Register-resident idx/c: this thread owns output quads q0 and q1 for all rows.
    const int q0 = tid, q1 = tid + T;
    const int4 iaA = ia4[q0], ibA = ib4[q0];
    const int4 iaB = ia4[q1], ibB = ib4[q1];
    const float4 cA0 = c[4*q0+0], cA1 = c[4*q0+1], cA2 = c[4*q0+2], cA3 = c[4*q0+3];
    const float4 cB0 = c[4*q1+0], cB1 = c[4*q1+1], cB2 = c[4*q1+2], cB3 = c[4*q1+3];

    // Prologue: stage row 0 into buf[0] (coalesced float4 sweep).
    {
        const float4* src4 = (const float4*)(x + r0 * IN_DIM);
        float4* dst4 = (float4*)buf[0];
        dst4[tid]     = src4[tid];
        dst4[tid + T] = src4[tid + T];
    }
    __syncthreads();

    int cur = 0;
    for (int r = 0; r < ROWS; ++r) {
        // (1) issue next-row prefetch early — lands during the gather phase
        float4 p0 = make_float4(0,0,0,0), p1 = make_float4(0,0,0,0);
        if (r + 1 < ROWS) {
            const float4* src4 = (const float4*)(x + (r0 + r + 1) * IN_DIM);
            p0 = src4[tid];
            p1 = src4[tid + T];
        }

        // (2) gather + compute + store current row
        const float* xr = buf[cur];
        float4* orow = out + (r0 + r) * (OUT_DIM / 4);
        {
            float a0 = xr[iaA.x], b0 = xr[ibA.x];
            float a1 = xr[iaA.y], b1 = xr[ibA.y];
            float a2 = xr[iaA.z], b2 = xr[ibA.z];
            float a3 = xr[iaA.w], b3 = xr[ibA.w];
            float4 o;
            o.x = fmaf(a0, fmaf(b0, cA0.w, cA0.y), fmaf(b0, cA0.z, cA0.x));
            o.y = fmaf(a1, fmaf(b1, cA1.w, cA1.y), fmaf(b1, cA1.z, cA1.x));
            o.z = fmaf(a2, fmaf(b2, cA2.w, cA2.y), fmaf(b2, cA2.z, cA2.x));
            o.w = fmaf(a3, fmaf(b3, cA3.w, cA3.y), fmaf(b3, cA3.z, cA3.x));
            orow[q0] = o;
        }
        {
            float a0 = xr[iaB.x], b0 = xr[ibB.x];
            float a1 = xr[iaB.y], b1 = xr[ibB.y];
            float a2 = xr[iaB.z], b2 = xr[ibB.z];
            float a3 = xr[iaB.w], b3 = xr[ibB.w];
            float4 o;
            o.x = fmaf(a0, fmaf(b0, cB0.w, cB0.y), fmaf(b0, cB0.z, cB0.x));
            o.y = fmaf(a1, fmaf(b1, cB1.w, cB1.y), fmaf(b1, cB1.z, cB1.x));
            o.z = fmaf(a2, fmaf(b2, cB2.w, cB2.y), fmaf(b2, cB2.z, cB2.x));
            o.w = fmaf(a3, fmaf(b3, cB3.w, cB3.y), fmaf(b3, cB3.z, cB3.x));
            orow[q1] = o;
        }

        // (3) write prefetched row into the other buffer, then one barrier
        if (r + 1 < ROWS) {
            float4* dst4 = (float4*)buf[cur ^ 1];
            dst4[tid]     = p0;
            dst4[tid + T] = p1;
        }
        __syncthreads();
        cur ^= 1;
    }
}

extern "C" void kernel_launch(void* const* d_in, const int* in_sizes, int n_in,
                              void* d_out, int out_size, void* d_ws, size_t ws_size,
                              hipStream_t stream) {
    const float* x      = (const float*)d_in[0];
    const float* weight = (const float*)d_in[1];
    const int*   idx_a  = (const int*)d_in[2];
    const int*   idx_b  = (const int*)d_in[3];
    float* out = (float*)d_out;

    float4* c = (float4*)d_ws;  // OUT_DIM float4 = 128 KB scratch

    compute_c_kernel<<<OUT_DIM / 256, 256, 0, stream>>>(weight, c);
    gate_main_kernel<<<BATCH / ROWS, T, 0, stream>>>(
        x, c, (const int4*)idx_a, (const int4*)idx_b, (float4*)out);
}